// Round 7
// baseline (1446.833 us; speedup 1.0000x reference)
//
#include <hip/hip_runtime.h>

// GINModel on MI355X (gfx950). Round 7: barrier-free GEMM K-loop.
//  - B (=W^T half-tile, 64KB) resident in LDS, loaded once per block
//  - A fragments loaded global->VGPR directly (coalesced 16x64B lines),
//    2-deep K-tile prefetch; NO per-tile barriers (m97-plateau lesson)
//  - XOR-swizzled Bs chunks: ds_read 2-way conflicts only (free)
//  - epilogue: scattered 2B stores (round-5-proven), BN stats from registers
// fp16 internal storage, fp32 accumulation, dual-width input hardening.

typedef __attribute__((ext_vector_type(4))) float f32x4;
typedef __attribute__((ext_vector_type(8))) _Float16 f16x8;

__device__ __forceinline__ float h2f(unsigned short u) {
  _Float16 h; __builtin_memcpy(&h, &u, 2); return (float)h;
}
__device__ __forceinline__ unsigned short f2h16(float f) {
  _Float16 h = (_Float16)f; unsigned short u; __builtin_memcpy(&u, &h, 2); return u;
}
__device__ __forceinline__ unsigned short f2b(float f) {  // fp32 -> bf16 RNE
  union { float f; unsigned int i; } c; c.f = f;
  unsigned int x = c.i;
  return (unsigned short)((x + 0x7fffu + ((x >> 16) & 1u)) >> 16);
}
__device__ __forceinline__ f16x8 asf16x8(uint4 v) {
  union { uint4 u; f16x8 h; } c; c.u = v; return c.h;
}
__device__ __forceinline__ float lin(const void* p, long long i, int wf32) {
  if (wf32) return ((const float*)p)[i];
  union { unsigned int i; float f; } c;
  c.i = ((unsigned int)((const unsigned short*)p)[i]) << 16;
  return c.f;
}
__device__ __forceinline__ int ldidx(const int* p, long long i, int w64) {
  return w64 ? p[2 * i] : p[i];
}

// flags[0]=w64 (int64 indices), flags[1]=wf32 (fp32 floats)
__global__ void detect_k(const int* __restrict__ edge, const unsigned short* __restrict__ xa,
                         int* __restrict__ flags) {
  if (threadIdx.x != 0 || blockIdx.x != 0) return;
  int nzOdd = 0;
  for (int t = 0; t < 256; t++) if (edge[2 * t + 1] != 0) nzOdd++;
  flags[0] = (nzOdd == 0) ? 1 : 0;
  int plaus = 0;
  for (int t = 0; t < 64; t++) {
    unsigned short w = xa[2 * t];
    int e = (w >> 7) & 0xFF;
    if (w == 0 || (e >= 0x70 && e <= 0x85)) plaus++;
  }
  flags[1] = (plaus < 32) ? 1 : 0;
}

__global__ void zero_i32_k(int* __restrict__ p, int n) {
  int i = blockIdx.x * blockDim.x + threadIdx.x;
  if (i < n) p[i] = 0;
}

// per-layer prep: slice 4x256 params to fp32 + zero BN accumulators
__global__ void prep_k(const void* __restrict__ b1, const void* __restrict__ b2,
                       const void* __restrict__ gm, const void* __restrict__ bt, int eoff,
                       float* __restrict__ pb1, float* __restrict__ pb2,
                       float* __restrict__ pg, float* __restrict__ pb,
                       float* __restrict__ gsum, const int* __restrict__ flags) {
  int wf32 = flags[1], t = threadIdx.x;
  pb1[t] = lin(b1, (long long)eoff + t, wf32);
  pb2[t] = lin(b2, (long long)eoff + t, wf32);
  pg[t]  = lin(gm, (long long)eoff + t, wf32);
  pb[t]  = lin(bt, (long long)eoff + t, wf32);
  gsum[t] = 0.f; gsum[256 + t] = 0.f;
}
__global__ void copy256_k(const void* __restrict__ src, int eoff, float* __restrict__ dst,
                          const int* __restrict__ flags) {
  dst[threadIdx.x] = lin(src, (long long)eoff + threadIdx.x, flags[1]);
}

// input (R x C at element offset, dual width) -> fp16 transposed (C x R)
__global__ void transpose_off_k(const void* __restrict__ src, long long eoff,
                                unsigned short* __restrict__ dst, int R, int C,
                                const int* __restrict__ flags) {
  int wf32 = flags[1];
  __shared__ unsigned short t[32][33];
  int bx = blockIdx.x * 32, by = blockIdx.y * 32;
  int x = bx + threadIdx.x;
  for (int i = 0; i < 32; i += 8) {
    int y = by + threadIdx.y + i;
    if (y < R && x < C)
      t[threadIdx.y + i][threadIdx.x] = f2h16(lin(src, eoff + (long long)y * C + x, wf32));
  }
  __syncthreads();
  int x2 = by + threadIdx.x;
  for (int i = 0; i < 32; i += 8) {
    int y = bx + threadIdx.y + i;
    if (y < C && x2 < R) dst[(long long)y * R + x2] = t[threadIdx.x][threadIdx.y + i];
  }
}

// ---------------- CSR ----------------
__global__ void hist_k(const int* __restrict__ edge, int E, int* __restrict__ cnt,
                       const int* __restrict__ flags) {
  int w64 = flags[0];
  int e = blockIdx.x * blockDim.x + threadIdx.x;
  if (e < E) atomicAdd(&cnt[ldidx(edge, (long long)E + e, w64)], 1);
}
#define SCAN_CHUNK 1024
__global__ void scan1_k(const int* __restrict__ in, int* __restrict__ out,
                        int* __restrict__ partials, int n) {
  __shared__ int sh[256];
  int tid = threadIdx.x;
  int base = blockIdx.x * SCAN_CHUNK + tid * 4;
  int v[4]; int tsum = 0;
#pragma unroll
  for (int i = 0; i < 4; i++) { v[i] = (base + i < n) ? in[base + i] : 0; tsum += v[i]; }
  sh[tid] = tsum; __syncthreads();
  for (int off = 1; off < 256; off <<= 1) {
    int t = (tid >= off) ? sh[tid - off] : 0;
    __syncthreads();
    sh[tid] += t;
    __syncthreads();
  }
  int run = sh[tid] - tsum;
#pragma unroll
  for (int i = 0; i < 4; i++) { if (base + i < n) out[base + i] = run; run += v[i]; }
  if (tid == 255) partials[blockIdx.x] = sh[255];
}
__global__ void scan2_k(int* partials, int B) {
  __shared__ int sh[256];
  int tid = threadIdx.x;
  int orig = (tid < B) ? partials[tid] : 0;
  sh[tid] = orig; __syncthreads();
  for (int off = 1; off < 256; off <<= 1) {
    int t = (tid >= off) ? sh[tid - off] : 0;
    __syncthreads();
    sh[tid] += t;
    __syncthreads();
  }
  if (tid < B) partials[tid] = sh[tid] - orig;
}
__global__ void scan3_k(int* __restrict__ out, const int* __restrict__ partials,
                        int n, int total) {
  int base = blockIdx.x * SCAN_CHUNK + threadIdx.x * 4;
  int add = partials[blockIdx.x];
#pragma unroll
  for (int i = 0; i < 4; i++) { if (base + i < n) out[base + i] += add; }
  if (blockIdx.x == 0 && threadIdx.x == 0) out[n] = total;
}
__global__ void fill_k(const int* __restrict__ edge, int E, const int* __restrict__ rowptr,
                       int* __restrict__ cnt, int* __restrict__ colidx,
                       const int* __restrict__ flags) {
  int w64 = flags[0];
  int e = blockIdx.x * blockDim.x + threadIdx.x;
  if (e >= E) return;
  int s = ldidx(edge, e, w64);
  int d = ldidx(edge, (long long)E + e, w64);
  int p = atomicAdd(&cnt[d], 1);
  colidx[rowptr[d] + p] = s;
}
__global__ void graph_bounds_k(const int* __restrict__ b, int Nn, int G,
                               int* __restrict__ gstart, const int* __restrict__ flags) {
  int w64 = flags[0];
  int g = blockIdx.x * blockDim.x + threadIdx.x;
  if (g > G) return;
  int lo = 0, hi = Nn;
  while (lo < hi) {
    int mid = (lo + hi) >> 1;
    if (ldidx(b, mid, w64) < g) lo = mid + 1; else hi = mid;
  }
  gstart[g] = lo;
}

// x (dual width) -> fp16
__global__ void convert_k(const void* __restrict__ x, unsigned short* __restrict__ xh,
                          long long n, const int* __restrict__ flags) {
  int wf32 = flags[1];
  long long base = ((long long)blockIdx.x * blockDim.x + threadIdx.x) * 4;
  if (base >= n) return;
#pragma unroll
  for (int k = 0; k < 4; k++) xh[base + k] = f2h16(lin(x, base + k, wf32));
}

// fused aggregation: u[i] = hn(i) + sum_{j in nbrs(i)} hn(j)
// hn = APPLY ? relu(v*scale+shift) : v.  LPN lanes per node, 8 fp16 per lane.
template <int LPN, int APPLY>
__global__ void gather_fused_k(const unsigned short* __restrict__ src,
                               const float* __restrict__ scale, const float* __restrict__ shift,
                               const int* __restrict__ rowptr, const int* __restrict__ colidx,
                               unsigned short* __restrict__ u, int Nn) {
  const int F = LPN * 8;
  int gid = blockIdx.x * blockDim.x + threadIdx.x;
  int node = gid / LPN;
  if (node >= Nn) return;
  int fb = (gid % LPN) * 8;
  float sc[8], sh[8];
  if (APPLY) {
#pragma unroll
    for (int k = 0; k < 8; k++) { sc[k] = scale[fb + k]; sh[k] = shift[fb + k]; }
  }
  float acc[8];
  {
    uint4 raw = *(const uint4*)(src + (long long)node * F + fb);
    unsigned int ws[4] = {raw.x, raw.y, raw.z, raw.w};
#pragma unroll
    for (int k = 0; k < 8; k++) {
      float xv = h2f((unsigned short)((ws[k >> 1] >> ((k & 1) * 16)) & 0xffff));
      acc[k] = APPLY ? fmaxf(xv * sc[k] + sh[k], 0.f) : xv;
    }
  }
  int s = rowptr[node], e = rowptr[node + 1];
  for (int j = s; j < e; j++) {
    long long nb = colidx[j];
    uint4 raw = *(const uint4*)(src + nb * F + fb);
    unsigned int ws[4] = {raw.x, raw.y, raw.z, raw.w};
#pragma unroll
    for (int k = 0; k < 8; k++) {
      float xv = h2f((unsigned short)((ws[k >> 1] >> ((k & 1) * 16)) & 0xffff));
      acc[k] += APPLY ? fmaxf(xv * sc[k] + sh[k], 0.f) : xv;
    }
  }
  uint4 o;
  unsigned int wo[4];
#pragma unroll
  for (int p = 0; p < 4; p++)
    wo[p] = (unsigned int)f2h16(acc[2 * p]) | ((unsigned int)f2h16(acc[2 * p + 1]) << 16);
  o.x = wo[0]; o.y = wo[1]; o.z = wo[2]; o.w = wo[3];
  *(uint4*)(u + (long long)node * F + fb) = o;
}

// Barrier-free MFMA fp16 GEMM.
// C(MxN=256) = act(A(MxK) @ W + bias_f32); Bt = W^T (256 x K), K in {128,256}.
// Block: 4 waves (2x2 of 64x64), tile 128x128 (grid.y = 2 N-halves).
// Bs holds the full 128xK B-half in LDS (XOR-chunk swizzle), loaded once.
// A fragments stream global->VGPR with 2-deep K-tile prefetch. One barrier total.
__global__ __launch_bounds__(256) void gemm_k(
    const unsigned short* __restrict__ A, const unsigned short* __restrict__ Bt,
    const float* __restrict__ bias, unsigned short* __restrict__ C,
    int M, int K, int relu, float* __restrict__ gsum) {
  __shared__ __align__(16) unsigned short Bs[128 * 256];  // 64 KB max (K=256)
  int m0 = blockIdx.x * 128, n0 = blockIdx.y * 128;
  int tid = threadIdx.x;
  int kchunks = K >> 3;  // 16B chunks per row
  for (int idx = tid; idx < 128 * kchunks; idx += 256) {
    int row = idx / kchunks, ch = idx - row * kchunks;
    *(uint4*)(Bs + row * K + ((ch ^ (row & 7)) << 3)) =
        *(const uint4*)(Bt + (long long)(n0 + row) * K + (ch << 3));
  }
  __syncthreads();  // the only barrier before the epilogue
  int wave = tid >> 6, lane = tid & 63;
  int wm = (wave >> 1) * 64, wn = (wave & 1) * 64;
  int lrow = lane & 15, lq = lane >> 4;
  long long aoff[4];
#pragma unroll
  for (int r = 0; r < 4; r++) {
    int row = m0 + wm + 16 * r + lrow;
    row = row < M ? row : M - 1;
    aoff[r] = (long long)row * K + lq * 8;
  }
  f32x4 acc[4][4] = {};
  int ktiles = K >> 5;           // 4 or 8
  int xr = lrow & 7;             // swizzle key
  uint4 af0[4], af1[4];
#pragma unroll
  for (int r = 0; r < 4; r++) af0[r] = *(const uint4*)(A + aoff[r]);
#pragma unroll
  for (int r = 0; r < 4; r++) af1[r] = *(const uint4*)(A + aoff[r] + 32);
  auto compute = [&](uint4 (&af)[4], int kb) {
    f16x8 b_[4];
    int ch = (kb >> 3) + lq;
#pragma unroll
    for (int c = 0; c < 4; c++) {
      int brow = wn + 16 * c + lrow;
      b_[c] = *(const f16x8*)(Bs + brow * K + ((ch ^ xr) << 3));
    }
#pragma unroll
    for (int r = 0; r < 4; r++) {
      f16x8 a_ = asf16x8(af[r]);
#pragma unroll
      for (int c = 0; c < 4; c++)
        acc[r][c] = __builtin_amdgcn_mfma_f32_16x16x32_f16(a_, b_[c], acc[r][c], 0, 0, 0);
    }
  };
  for (int kt = 0; kt < ktiles; kt += 2) {
    compute(af0, kt << 5);
    if (kt + 2 < ktiles) {
      int kb2 = (kt + 2) << 5;
#pragma unroll
      for (int r = 0; r < 4; r++) af0[r] = *(const uint4*)(A + aoff[r] + kb2);
    }
    compute(af1, (kt + 1) << 5);
    if (kt + 3 < ktiles) {
      int kb3 = (kt + 3) << 5;
#pragma unroll
      for (int r = 0; r < 4; r++) af1[r] = *(const uint4*)(A + aoff[r] + kb3);
    }
  }
  // ---- epilogue: scattered stores + register-sourced BN stats ----
  bool dostats = (gsum != nullptr);
  float scol[4], qcol[4];
#pragma unroll
  for (int c = 0; c < 4; c++) {
    int col = n0 + wn + 16 * c + lrow;
    float bv = bias[col];
    float s = 0.f, q = 0.f;
#pragma unroll
    for (int r = 0; r < 4; r++) {
      int rbase = m0 + wm + 16 * r + lq * 4;
#pragma unroll
      for (int i = 0; i < 4; i++) {
        int row = rbase + i;
        if (row < M) {
          float v = acc[r][c][i] + bv;
          if (relu) v = fmaxf(v, 0.f);
          C[(long long)row * 256 + col] = f2h16(v);
          s += v; q += v * v;
        }
      }
    }
    scol[c] = s; qcol[c] = q;
  }
  if (dostats) {
#pragma unroll
    for (int c = 0; c < 4; c++) {
      scol[c] += __shfl_xor(scol[c], 16); scol[c] += __shfl_xor(scol[c], 32);
      qcol[c] += __shfl_xor(qcol[c], 16); qcol[c] += __shfl_xor(qcol[c], 32);
    }
    float* lf = (float*)Bs;
    __syncthreads();
    if (tid < 256) lf[tid] = 0.f;
    __syncthreads();
    if (lq == 0) {
#pragma unroll
      for (int c = 0; c < 4; c++) {
        atomicAdd(&lf[wn + 16 * c + lrow], scol[c]);
        atomicAdd(&lf[128 + wn + 16 * c + lrow], qcol[c]);
      }
    }
    __syncthreads();
    if (tid < 128) {
      atomicAdd(&gsum[n0 + tid], lf[tid]);
      atomicAdd(&gsum[256 + n0 + tid], lf[128 + tid]);
    }
  }
}

__global__ void bn_finalize_k(const float* __restrict__ gsum,
                              const float* __restrict__ pg, const float* __restrict__ pb,
                              int Nn, float* __restrict__ scale, float* __restrict__ shift) {
  int f = threadIdx.x;
  float inv = 1.f / (float)Nn;
  float mean = gsum[f] * inv;
  float var = fmaxf(gsum[256 + f] * inv - mean * mean, 0.f);
  float sc = pg[f] * rsqrtf(var + 1e-5f);
  scale[f] = sc;
  shift[f] = pb[f] - mean * sc;
}

// fused pool: mean over graph rows of relu(v*sc+sh)
__global__ void pool_fused_k(const unsigned short* __restrict__ v, const float* __restrict__ scale,
                             const float* __restrict__ shift, const int* __restrict__ gstart,
                             unsigned short* __restrict__ gout) {
  int g = blockIdx.x, f = threadIdx.x;
  int s = gstart[g], e = gstart[g + 1];
  float sc = scale[f], sh = shift[f];
  float acc = 0.f;
  for (int r = s; r < e; r++) acc += fmaxf(h2f(v[(long long)r * 256 + f]) * sc + sh, 0.f);
  gout[(long long)g * 256 + f] = f2h16(acc / fmaxf((float)(e - s), 1.f));
}
__global__ void pred2_k(const unsigned short* __restrict__ p1, const void* __restrict__ Wp2,
                        const void* __restrict__ bp2, void* __restrict__ out, int G,
                        const int* __restrict__ flags) {
  int wf32 = flags[1];
  int idx = blockIdx.x * blockDim.x + threadIdx.x;
  if (idx >= G * 12) return;
  int g = idx / 12, t = idx - g * 12;
  float acc = lin(bp2, t, wf32);
  const unsigned short* row = p1 + (long long)g * 256;
  for (int k = 0; k < 256; k++) acc += h2f(row[k]) * lin(Wp2, k * 12 + t, wf32);
  if (wf32) ((float*)out)[idx] = acc;
  else      ((unsigned short*)out)[idx] = f2b(acc);
}

extern "C" void kernel_launch(void* const* d_in, const int* in_sizes, int n_in,
                              void* d_out, int out_size, void* d_ws, size_t ws_size,
                              hipStream_t stream) {
  int wb = -1;
  for (int i = 3; i + 15 < n_in; i++) {
    if (in_sizes[i] == 32768 && in_sizes[i + 1] == 256 && in_sizes[i + 2] == 65536 &&
        in_sizes[i + 3] == 256 && in_sizes[i + 4] == 256 && in_sizes[i + 5] == 256 &&
        in_sizes[i + 6] == 262144) { wb = i; break; }
  }
  if (wb < 0) wb = (n_in >= 20) ? 4 : 3;

  const void* x      = d_in[0];
  const int*  edge   = (const int*)d_in[1];
  const int*  batch  = (const int*)d_in[2];
  const void* W1_0   = d_in[wb + 0];
  const void* b1_0   = d_in[wb + 1];
  const void* W2_0   = d_in[wb + 2];
  const void* b2_0   = d_in[wb + 3];
  const void* gamma0 = d_in[wb + 4];
  const void* beta0  = d_in[wb + 5];
  const void* W1s    = d_in[wb + 6];
  const void* b1s    = d_in[wb + 7];
  const void* W2s    = d_in[wb + 8];
  const void* b2s    = d_in[wb + 9];
  const void* gammas = d_in[wb + 10];
  const void* betas  = d_in[wb + 11];
  const void* Wp1    = d_in[wb + 12];
  const void* bp1    = d_in[wb + 13];
  const void* Wp2    = d_in[wb + 14];
  const void* bp2    = d_in[wb + 15];

  const int N = in_sizes[0] / 128;
  const int E = in_sizes[1] / 2;
  const int G = out_size / 12;
  const int H = 256;

  char* w = (char*)d_ws;
  size_t off = 0;
  auto alloc = [&](size_t bytes) -> char* {
    char* p = w + off;
    off += (bytes + 255) & ~(size_t)255;
    return p;
  };
  unsigned short* bufX  = (unsigned short*)alloc((size_t)N * H * 2);
  unsigned short* bufY  = (unsigned short*)alloc((size_t)N * H * 2);  // xh parks here first
  unsigned short* w1_0t = (unsigned short*)alloc((size_t)128 * 256 * 2);
  unsigned short* w2_0t = (unsigned short*)alloc((size_t)256 * 256 * 2);
  unsigned short* w1st  = (unsigned short*)alloc((size_t)4 * 256 * 256 * 2);
  unsigned short* w2st  = (unsigned short*)alloc((size_t)4 * 256 * 256 * 2);
  unsigned short* wp1t  = (unsigned short*)alloc((size_t)256 * 256 * 2);
  int*   rowptr   = (int*)alloc((size_t)(N + 1) * 4);
  int*   cnt      = (int*)alloc((size_t)N * 4);
  int*   colidx   = (int*)alloc((size_t)E * 4);
  int*   partials = (int*)alloc(1024 * 4);
  float* gsum     = (float*)alloc(512 * 4);
  float* bnscale  = (float*)alloc(256 * 4);
  float* bnshift  = (float*)alloc(256 * 4);
  float* pg       = (float*)alloc(256 * 4);
  float* pb       = (float*)alloc(256 * 4);
  float* pb1      = (float*)alloc(256 * 4);
  float* pb2      = (float*)alloc(256 * 4);
  int*   gstart   = (int*)alloc((size_t)(G + 1) * 4);
  int*   flags    = (int*)alloc(256);
  unsigned short* gpool = (unsigned short*)alloc((size_t)G * H * 2);
  unsigned short* p1    = (unsigned short*)alloc((size_t)G * H * 2);
  (void)ws_size; (void)n_in;

  detect_k<<<1, 64, 0, stream>>>(edge, (const unsigned short*)x, flags);

  // x -> fp16 into bufY (dead once layer-0 gemm1 overwrites bufY)
  convert_k<<<(int)(((long long)N * 128 / 4 + 255) / 256), 256, 0, stream>>>(
      x, bufY, (long long)N * 128, flags);

  dim3 tb(32, 8);
  auto transpose = [&](const void* src, long long eoff, unsigned short* dst, int R, int C) {
    transpose_off_k<<<dim3((C + 31) / 32, (R + 31) / 32), tb, 0, stream>>>(src, eoff, dst, R, C, flags);
  };
  transpose(W1_0, 0, w1_0t, 128, 256);
  transpose(W2_0, 0, w2_0t, 256, 256);
  for (int i = 0; i < 4; i++) {
    transpose(W1s, (long long)i * 65536, w1st + i * 65536, 256, 256);
    transpose(W2s, (long long)i * 65536, w2st + i * 65536, 256, 256);
  }
  transpose(Wp1, 0, wp1t, 256, 256);

  // CSR
  zero_i32_k<<<(N + 255) / 256, 256, 0, stream>>>(cnt, N);
  hist_k<<<(E + 255) / 256, 256, 0, stream>>>(edge, E, cnt, flags);
  int NB = (N + SCAN_CHUNK - 1) / SCAN_CHUNK;
  scan1_k<<<NB, 256, 0, stream>>>(cnt, rowptr, partials, N);
  scan2_k<<<1, 256, 0, stream>>>(partials, NB);
  scan3_k<<<NB, 256, 0, stream>>>(rowptr, partials, N, E);
  zero_i32_k<<<(N + 255) / 256, 256, 0, stream>>>(cnt, N);
  fill_k<<<(E + 255) / 256, 256, 0, stream>>>(edge, E, rowptr, cnt, colidx, flags);
  graph_bounds_k<<<(G + 1 + 255) / 256, 256, 0, stream>>>(batch, N, G, gstart, flags);

  auto gemm = [&](const unsigned short* A, const unsigned short* Bt, const float* bias,
                  unsigned short* Cq, int M, int K, int relu, float* stats) {
    gemm_k<<<dim3((M + 127) / 128, 2), 256, 0, stream>>>(A, Bt, bias, Cq, M, K, relu, stats);
  };

  // ---- layer 0 ----
  prep_k<<<1, 256, 0, stream>>>(b1_0, b2_0, gamma0, beta0, 0, pb1, pb2, pg, pb, gsum, flags);
  gather_fused_k<16, 0><<<(N * 16 + 255) / 256, 256, 0, stream>>>(
      bufY, bnscale, bnshift, rowptr, colidx, bufX, N);
  gemm(bufX, w1_0t, pb1, bufY, N, 128, 1, nullptr);
  gemm(bufY, w2_0t, pb2, bufX, N, 256, 0, gsum);   // v0 + fused BN stats
  bn_finalize_k<<<1, 256, 0, stream>>>(gsum, pg, pb, N, bnscale, bnshift);
  unsigned short* cur = bufX;  // pre-BN v0
  unsigned short* oth = bufY;
  // ---- layers 1..4 ----
  for (int i = 0; i < 4; i++) {
    prep_k<<<1, 256, 0, stream>>>(b1s, b2s, gammas, betas, i * 256, pb1, pb2, pg, pb, gsum, flags);
    gather_fused_k<32, 1><<<(N * 32 + 255) / 256, 256, 0, stream>>>(
        cur, bnscale, bnshift, rowptr, colidx, oth, N);
    gemm(oth, w1st + i * 65536, pb1, cur, N, 256, 1, nullptr);
    gemm(cur, w2st + i * 65536, pb2, oth, N, 256, 0, gsum);  // v_i + BN stats
    bn_finalize_k<<<1, 256, 0, stream>>>(gsum, pg, pb, N, bnscale, bnshift);
    unsigned short* t = cur; cur = oth; oth = t;  // v_i now in cur
  }

  // ---- pool + predictor ----
  copy256_k<<<1, 256, 0, stream>>>(bp1, 0, pb1, flags);
  pool_fused_k<<<G, 256, 0, stream>>>(cur, bnscale, bnshift, gstart, gpool);
  gemm(gpool, wp1t, pb1, p1, G, 256, 1, nullptr);
  pred2_k<<<(G * 12 + 255) / 256, 256, 0, stream>>>(p1, Wp2, bp2, d_out, G, flags);
}

// Round 8
// 1391.442 us; speedup vs baseline: 1.0398x; 1.0398x over previous
//
#include <hip/hip_runtime.h>

// GINModel on MI355X (gfx950). Round 8: LDS-free barrier-free GEMM.
// r7 lesson: 64KB LDS -> 2 blocks/CU -> stalls. B's MFMA fragment pattern
// equals A's (Bt row n, 16B chunk at lq*8), so load BOTH operands
// global->VGPR directly (B hits L2, ~128KB hot). No staging, no barriers,
// 2-deep K-tile prefetch on A and B, __launch_bounds__(256,3) to keep
// >=3 waves/SIMD. Epilogue: scattered stores (r5-proven) + register BN stats.
// fp16 internal storage, fp32 accumulation, dual-width input hardening.

typedef __attribute__((ext_vector_type(4))) float f32x4;
typedef __attribute__((ext_vector_type(8))) _Float16 f16x8;

__device__ __forceinline__ float h2f(unsigned short u) {
  _Float16 h; __builtin_memcpy(&h, &u, 2); return (float)h;
}
__device__ __forceinline__ unsigned short f2h16(float f) {
  _Float16 h = (_Float16)f; unsigned short u; __builtin_memcpy(&u, &h, 2); return u;
}
__device__ __forceinline__ unsigned short f2b(float f) {  // fp32 -> bf16 RNE
  union { float f; unsigned int i; } c; c.f = f;
  unsigned int x = c.i;
  return (unsigned short)((x + 0x7fffu + ((x >> 16) & 1u)) >> 16);
}
__device__ __forceinline__ f16x8 asf16x8(uint4 v) {
  union { uint4 u; f16x8 h; } c; c.u = v; return c.h;
}
__device__ __forceinline__ float lin(const void* p, long long i, int wf32) {
  if (wf32) return ((const float*)p)[i];
  union { unsigned int i; float f; } c;
  c.i = ((unsigned int)((const unsigned short*)p)[i]) << 16;
  return c.f;
}
__device__ __forceinline__ int ldidx(const int* p, long long i, int w64) {
  return w64 ? p[2 * i] : p[i];
}

// flags[0]=w64 (int64 indices), flags[1]=wf32 (fp32 floats)
__global__ void detect_k(const int* __restrict__ edge, const unsigned short* __restrict__ xa,
                         int* __restrict__ flags) {
  if (threadIdx.x != 0 || blockIdx.x != 0) return;
  int nzOdd = 0;
  for (int t = 0; t < 256; t++) if (edge[2 * t + 1] != 0) nzOdd++;
  flags[0] = (nzOdd == 0) ? 1 : 0;
  int plaus = 0;
  for (int t = 0; t < 64; t++) {
    unsigned short w = xa[2 * t];
    int e = (w >> 7) & 0xFF;
    if (w == 0 || (e >= 0x70 && e <= 0x85)) plaus++;
  }
  flags[1] = (plaus < 32) ? 1 : 0;
}

__global__ void zero_i32_k(int* __restrict__ p, int n) {
  int i = blockIdx.x * blockDim.x + threadIdx.x;
  if (i < n) p[i] = 0;
}

// per-layer prep: slice 4x256 params to fp32 + zero BN accumulators
__global__ void prep_k(const void* __restrict__ b1, const void* __restrict__ b2,
                       const void* __restrict__ gm, const void* __restrict__ bt, int eoff,
                       float* __restrict__ pb1, float* __restrict__ pb2,
                       float* __restrict__ pg, float* __restrict__ pb,
                       float* __restrict__ gsum, const int* __restrict__ flags) {
  int wf32 = flags[1], t = threadIdx.x;
  pb1[t] = lin(b1, (long long)eoff + t, wf32);
  pb2[t] = lin(b2, (long long)eoff + t, wf32);
  pg[t]  = lin(gm, (long long)eoff + t, wf32);
  pb[t]  = lin(bt, (long long)eoff + t, wf32);
  gsum[t] = 0.f; gsum[256 + t] = 0.f;
}
__global__ void copy256_k(const void* __restrict__ src, int eoff, float* __restrict__ dst,
                          const int* __restrict__ flags) {
  dst[threadIdx.x] = lin(src, (long long)eoff + threadIdx.x, flags[1]);
}

// input (R x C at element offset, dual width) -> fp16 transposed (C x R)
__global__ void transpose_off_k(const void* __restrict__ src, long long eoff,
                                unsigned short* __restrict__ dst, int R, int C,
                                const int* __restrict__ flags) {
  int wf32 = flags[1];
  __shared__ unsigned short t[32][33];
  int bx = blockIdx.x * 32, by = blockIdx.y * 32;
  int x = bx + threadIdx.x;
  for (int i = 0; i < 32; i += 8) {
    int y = by + threadIdx.y + i;
    if (y < R && x < C)
      t[threadIdx.y + i][threadIdx.x] = f2h16(lin(src, eoff + (long long)y * C + x, wf32));
  }
  __syncthreads();
  int x2 = by + threadIdx.x;
  for (int i = 0; i < 32; i += 8) {
    int y = bx + threadIdx.y + i;
    if (y < C && x2 < R) dst[(long long)y * R + x2] = t[threadIdx.x][threadIdx.y + i];
  }
}

// ---------------- CSR ----------------
__global__ void hist_k(const int* __restrict__ edge, int E, int* __restrict__ cnt,
                       const int* __restrict__ flags) {
  int w64 = flags[0];
  int e = blockIdx.x * blockDim.x + threadIdx.x;
  if (e < E) atomicAdd(&cnt[ldidx(edge, (long long)E + e, w64)], 1);
}
#define SCAN_CHUNK 1024
__global__ void scan1_k(const int* __restrict__ in, int* __restrict__ out,
                        int* __restrict__ partials, int n) {
  __shared__ int sh[256];
  int tid = threadIdx.x;
  int base = blockIdx.x * SCAN_CHUNK + tid * 4;
  int v[4]; int tsum = 0;
#pragma unroll
  for (int i = 0; i < 4; i++) { v[i] = (base + i < n) ? in[base + i] : 0; tsum += v[i]; }
  sh[tid] = tsum; __syncthreads();
  for (int off = 1; off < 256; off <<= 1) {
    int t = (tid >= off) ? sh[tid - off] : 0;
    __syncthreads();
    sh[tid] += t;
    __syncthreads();
  }
  int run = sh[tid] - tsum;
#pragma unroll
  for (int i = 0; i < 4; i++) { if (base + i < n) out[base + i] = run; run += v[i]; }
  if (tid == 255) partials[blockIdx.x] = sh[255];
}
__global__ void scan2_k(int* partials, int B) {
  __shared__ int sh[256];
  int tid = threadIdx.x;
  int orig = (tid < B) ? partials[tid] : 0;
  sh[tid] = orig; __syncthreads();
  for (int off = 1; off < 256; off <<= 1) {
    int t = (tid >= off) ? sh[tid - off] : 0;
    __syncthreads();
    sh[tid] += t;
    __syncthreads();
  }
  if (tid < B) partials[tid] = sh[tid] - orig;
}
__global__ void scan3_k(int* __restrict__ out, const int* __restrict__ partials,
                        int n, int total) {
  int base = blockIdx.x * SCAN_CHUNK + threadIdx.x * 4;
  int add = partials[blockIdx.x];
#pragma unroll
  for (int i = 0; i < 4; i++) { if (base + i < n) out[base + i] += add; }
  if (blockIdx.x == 0 && threadIdx.x == 0) out[n] = total;
}
__global__ void fill_k(const int* __restrict__ edge, int E, const int* __restrict__ rowptr,
                       int* __restrict__ cnt, int* __restrict__ colidx,
                       const int* __restrict__ flags) {
  int w64 = flags[0];
  int e = blockIdx.x * blockDim.x + threadIdx.x;
  if (e >= E) return;
  int s = ldidx(edge, e, w64);
  int d = ldidx(edge, (long long)E + e, w64);
  int p = atomicAdd(&cnt[d], 1);
  colidx[rowptr[d] + p] = s;
}
__global__ void graph_bounds_k(const int* __restrict__ b, int Nn, int G,
                               int* __restrict__ gstart, const int* __restrict__ flags) {
  int w64 = flags[0];
  int g = blockIdx.x * blockDim.x + threadIdx.x;
  if (g > G) return;
  int lo = 0, hi = Nn;
  while (lo < hi) {
    int mid = (lo + hi) >> 1;
    if (ldidx(b, mid, w64) < g) lo = mid + 1; else hi = mid;
  }
  gstart[g] = lo;
}

// x (dual width) -> fp16
__global__ void convert_k(const void* __restrict__ x, unsigned short* __restrict__ xh,
                          long long n, const int* __restrict__ flags) {
  int wf32 = flags[1];
  long long base = ((long long)blockIdx.x * blockDim.x + threadIdx.x) * 4;
  if (base >= n) return;
#pragma unroll
  for (int k = 0; k < 4; k++) xh[base + k] = f2h16(lin(x, base + k, wf32));
}

// fused aggregation: u[i] = hn(i) + sum_{j in nbrs(i)} hn(j)
// hn = APPLY ? relu(v*scale+shift) : v.  LPN lanes per node, 8 fp16 per lane.
template <int LPN, int APPLY>
__global__ void gather_fused_k(const unsigned short* __restrict__ src,
                               const float* __restrict__ scale, const float* __restrict__ shift,
                               const int* __restrict__ rowptr, const int* __restrict__ colidx,
                               unsigned short* __restrict__ u, int Nn) {
  const int F = LPN * 8;
  int gid = blockIdx.x * blockDim.x + threadIdx.x;
  int node = gid / LPN;
  if (node >= Nn) return;
  int fb = (gid % LPN) * 8;
  float sc[8], sh[8];
  if (APPLY) {
#pragma unroll
    for (int k = 0; k < 8; k++) { sc[k] = scale[fb + k]; sh[k] = shift[fb + k]; }
  }
  float acc[8];
  {
    uint4 raw = *(const uint4*)(src + (long long)node * F + fb);
    unsigned int ws[4] = {raw.x, raw.y, raw.z, raw.w};
#pragma unroll
    for (int k = 0; k < 8; k++) {
      float xv = h2f((unsigned short)((ws[k >> 1] >> ((k & 1) * 16)) & 0xffff));
      acc[k] = APPLY ? fmaxf(xv * sc[k] + sh[k], 0.f) : xv;
    }
  }
  int s = rowptr[node], e = rowptr[node + 1];
  for (int j = s; j < e; j++) {
    long long nb = colidx[j];
    uint4 raw = *(const uint4*)(src + nb * F + fb);
    unsigned int ws[4] = {raw.x, raw.y, raw.z, raw.w};
#pragma unroll
    for (int k = 0; k < 8; k++) {
      float xv = h2f((unsigned short)((ws[k >> 1] >> ((k & 1) * 16)) & 0xffff));
      acc[k] += APPLY ? fmaxf(xv * sc[k] + sh[k], 0.f) : xv;
    }
  }
  uint4 o;
  unsigned int wo[4];
#pragma unroll
  for (int p = 0; p < 4; p++)
    wo[p] = (unsigned int)f2h16(acc[2 * p]) | ((unsigned int)f2h16(acc[2 * p + 1]) << 16);
  o.x = wo[0]; o.y = wo[1]; o.z = wo[2]; o.w = wo[3];
  *(uint4*)(u + (long long)node * F + fb) = o;
}

// LDS-free barrier-free MFMA fp16 GEMM.
// C(MxN=256) = act(A(MxK) @ W + bias_f32); Bt = W^T (256 x K), K in {128,256}.
// Block: 4 waves (2x2 of 64x64), tile 128x128 (grid.y = 2 N-halves).
// A and B fragments both global->VGPR (same pattern: row, 16B chunk at lq*8),
// 2-deep K-tile prefetch. B is L2-hot (128KB). No barriers in the K-loop.
__global__ __launch_bounds__(256, 3) void gemm_k(
    const unsigned short* __restrict__ A, const unsigned short* __restrict__ Bt,
    const float* __restrict__ bias, unsigned short* __restrict__ C,
    int M, int K, int relu, float* __restrict__ gsum) {
  int m0 = blockIdx.x * 128, n0 = blockIdx.y * 128;
  int tid = threadIdx.x;
  int wave = tid >> 6, lane = tid & 63;
  int wm = (wave >> 1) * 64, wn = (wave & 1) * 64;
  int lrow = lane & 15, lq = lane >> 4;
  long long aoff[4], boff[4];
#pragma unroll
  for (int r = 0; r < 4; r++) {
    int row = m0 + wm + 16 * r + lrow;
    row = row < M ? row : M - 1;
    aoff[r] = (long long)row * K + lq * 8;
    boff[r] = (long long)(n0 + wn + 16 * r + lrow) * K + lq * 8;
  }
  f32x4 acc[4][4] = {};
  int ktiles = K >> 5;           // 4 or 8
  uint4 af0[4], af1[4], bf0[4], bf1[4];
#pragma unroll
  for (int r = 0; r < 4; r++) {
    af0[r] = *(const uint4*)(A + aoff[r]);
    bf0[r] = *(const uint4*)(Bt + boff[r]);
  }
#pragma unroll
  for (int r = 0; r < 4; r++) {
    af1[r] = *(const uint4*)(A + aoff[r] + 32);
    bf1[r] = *(const uint4*)(Bt + boff[r] + 32);
  }
  auto compute = [&](uint4 (&af)[4], uint4 (&bf)[4]) {
#pragma unroll
    for (int r = 0; r < 4; r++) {
      f16x8 a_ = asf16x8(af[r]);
#pragma unroll
      for (int c = 0; c < 4; c++)
        acc[r][c] = __builtin_amdgcn_mfma_f32_16x16x32_f16(a_, asf16x8(bf[c]), acc[r][c], 0, 0, 0);
    }
  };
  for (int kt = 0; kt < ktiles; kt += 2) {
    compute(af0, bf0);
    if (kt + 2 < ktiles) {
      int kb2 = (kt + 2) << 5;
#pragma unroll
      for (int r = 0; r < 4; r++) {
        af0[r] = *(const uint4*)(A + aoff[r] + kb2);
        bf0[r] = *(const uint4*)(Bt + boff[r] + kb2);
      }
    }
    compute(af1, bf1);
    if (kt + 3 < ktiles) {
      int kb3 = (kt + 3) << 5;
#pragma unroll
      for (int r = 0; r < 4; r++) {
        af1[r] = *(const uint4*)(A + aoff[r] + kb3);
        bf1[r] = *(const uint4*)(Bt + boff[r] + kb3);
      }
    }
  }
  // ---- epilogue: scattered stores + register-sourced BN stats ----
  bool dostats = (gsum != nullptr);
  float scol[4], qcol[4];
#pragma unroll
  for (int c = 0; c < 4; c++) {
    int col = n0 + wn + 16 * c + lrow;
    float bv = bias[col];
    float s = 0.f, q = 0.f;
#pragma unroll
    for (int r = 0; r < 4; r++) {
      int rbase = m0 + wm + 16 * r + lq * 4;
#pragma unroll
      for (int i = 0; i < 4; i++) {
        int row = rbase + i;
        if (row < M) {
          float v = acc[r][c][i] + bv;
          if (relu) v = fmaxf(v, 0.f);
          C[(long long)row * 256 + col] = f2h16(v);
          s += v; q += v * v;
        }
      }
    }
    scol[c] = s; qcol[c] = q;
  }
  if (dostats) {
    __shared__ float lf[256];
#pragma unroll
    for (int c = 0; c < 4; c++) {
      scol[c] += __shfl_xor(scol[c], 16); scol[c] += __shfl_xor(scol[c], 32);
      qcol[c] += __shfl_xor(qcol[c], 16); qcol[c] += __shfl_xor(qcol[c], 32);
    }
    if (tid < 256) lf[tid] = 0.f;
    __syncthreads();
    if (lq == 0) {
#pragma unroll
      for (int c = 0; c < 4; c++) {
        atomicAdd(&lf[wn + 16 * c + lrow], scol[c]);
        atomicAdd(&lf[128 + wn + 16 * c + lrow], qcol[c]);
      }
    }
    __syncthreads();
    if (tid < 128) {
      atomicAdd(&gsum[n0 + tid], lf[tid]);
      atomicAdd(&gsum[256 + n0 + tid], lf[128 + tid]);
    }
  }
}

__global__ void bn_finalize_k(const float* __restrict__ gsum,
                              const float* __restrict__ pg, const float* __restrict__ pb,
                              int Nn, float* __restrict__ scale, float* __restrict__ shift) {
  int f = threadIdx.x;
  float inv = 1.f / (float)Nn;
  float mean = gsum[f] * inv;
  float var = fmaxf(gsum[256 + f] * inv - mean * mean, 0.f);
  float sc = pg[f] * rsqrtf(var + 1e-5f);
  scale[f] = sc;
  shift[f] = pb[f] - mean * sc;
}

// fused pool: mean over graph rows of relu(v*sc+sh)
__global__ void pool_fused_k(const unsigned short* __restrict__ v, const float* __restrict__ scale,
                             const float* __restrict__ shift, const int* __restrict__ gstart,
                             unsigned short* __restrict__ gout) {
  int g = blockIdx.x, f = threadIdx.x;
  int s = gstart[g], e = gstart[g + 1];
  float sc = scale[f], sh = shift[f];
  float acc = 0.f;
  for (int r = s; r < e; r++) acc += fmaxf(h2f(v[(long long)r * 256 + f]) * sc + sh, 0.f);
  gout[(long long)g * 256 + f] = f2h16(acc / fmaxf((float)(e - s), 1.f));
}
__global__ void pred2_k(const unsigned short* __restrict__ p1, const void* __restrict__ Wp2,
                        const void* __restrict__ bp2, void* __restrict__ out, int G,
                        const int* __restrict__ flags) {
  int wf32 = flags[1];
  int idx = blockIdx.x * blockDim.x + threadIdx.x;
  if (idx >= G * 12) return;
  int g = idx / 12, t = idx - g * 12;
  float acc = lin(bp2, t, wf32);
  const unsigned short* row = p1 + (long long)g * 256;
  for (int k = 0; k < 256; k++) acc += h2f(row[k]) * lin(Wp2, k * 12 + t, wf32);
  if (wf32) ((float*)out)[idx] = acc;
  else      ((unsigned short*)out)[idx] = f2b(acc);
}

extern "C" void kernel_launch(void* const* d_in, const int* in_sizes, int n_in,
                              void* d_out, int out_size, void* d_ws, size_t ws_size,
                              hipStream_t stream) {
  int wb = -1;
  for (int i = 3; i + 15 < n_in; i++) {
    if (in_sizes[i] == 32768 && in_sizes[i + 1] == 256 && in_sizes[i + 2] == 65536 &&
        in_sizes[i + 3] == 256 && in_sizes[i + 4] == 256 && in_sizes[i + 5] == 256 &&
        in_sizes[i + 6] == 262144) { wb = i; break; }
  }
  if (wb < 0) wb = (n_in >= 20) ? 4 : 3;

  const void* x      = d_in[0];
  const int*  edge   = (const int*)d_in[1];
  const int*  batch  = (const int*)d_in[2];
  const void* W1_0   = d_in[wb + 0];
  const void* b1_0   = d_in[wb + 1];
  const void* W2_0   = d_in[wb + 2];
  const void* b2_0   = d_in[wb + 3];
  const void* gamma0 = d_in[wb + 4];
  const void* beta0  = d_in[wb + 5];
  const void* W1s    = d_in[wb + 6];
  const void* b1s    = d_in[wb + 7];
  const void* W2s    = d_in[wb + 8];
  const void* b2s    = d_in[wb + 9];
  const void* gammas = d_in[wb + 10];
  const void* betas  = d_in[wb + 11];
  const void* Wp1    = d_in[wb + 12];
  const void* bp1    = d_in[wb + 13];
  const void* Wp2    = d_in[wb + 14];
  const void* bp2    = d_in[wb + 15];

  const int N = in_sizes[0] / 128;
  const int E = in_sizes[1] / 2;
  const int G = out_size / 12;
  const int H = 256;

  char* w = (char*)d_ws;
  size_t off = 0;
  auto alloc = [&](size_t bytes) -> char* {
    char* p = w + off;
    off += (bytes + 255) & ~(size_t)255;
    return p;
  };
  unsigned short* bufX  = (unsigned short*)alloc((size_t)N * H * 2);
  unsigned short* bufY  = (unsigned short*)alloc((size_t)N * H * 2);  // xh parks here first
  unsigned short* w1_0t = (unsigned short*)alloc((size_t)128 * 256 * 2);
  unsigned short* w2_0t = (unsigned short*)alloc((size_t)256 * 256 * 2);
  unsigned short* w1st  = (unsigned short*)alloc((size_t)4 * 256 * 256 * 2);
  unsigned short* w2st  = (unsigned short*)alloc((size_t)4 * 256 * 256 * 2);
  unsigned short* wp1t  = (unsigned short*)alloc((size_t)256 * 256 * 2);
  int*   rowptr   = (int*)alloc((size_t)(N + 1) * 4);
  int*   cnt      = (int*)alloc((size_t)N * 4);
  int*   colidx   = (int*)alloc((size_t)E * 4);
  int*   partials = (int*)alloc(1024 * 4);
  float* gsum     = (float*)alloc(512 * 4);
  float* bnscale  = (float*)alloc(256 * 4);
  float* bnshift  = (float*)alloc(256 * 4);
  float* pg       = (float*)alloc(256 * 4);
  float* pb       = (float*)alloc(256 * 4);
  float* pb1      = (float*)alloc(256 * 4);
  float* pb2      = (float*)alloc(256 * 4);
  int*   gstart   = (int*)alloc((size_t)(G + 1) * 4);
  int*   flags    = (int*)alloc(256);
  unsigned short* gpool = (unsigned short*)alloc((size_t)G * H * 2);
  unsigned short* p1    = (unsigned short*)alloc((size_t)G * H * 2);
  (void)ws_size; (void)n_in;

  detect_k<<<1, 64, 0, stream>>>(edge, (const unsigned short*)x, flags);

  // x -> fp16 into bufY (dead once layer-0 gemm1 overwrites bufY)
  convert_k<<<(int)(((long long)N * 128 / 4 + 255) / 256), 256, 0, stream>>>(
      x, bufY, (long long)N * 128, flags);

  dim3 tb(32, 8);
  auto transpose = [&](const void* src, long long eoff, unsigned short* dst, int R, int C) {
    transpose_off_k<<<dim3((C + 31) / 32, (R + 31) / 32), tb, 0, stream>>>(src, eoff, dst, R, C, flags);
  };
  transpose(W1_0, 0, w1_0t, 128, 256);
  transpose(W2_0, 0, w2_0t, 256, 256);
  for (int i = 0; i < 4; i++) {
    transpose(W1s, (long long)i * 65536, w1st + i * 65536, 256, 256);
    transpose(W2s, (long long)i * 65536, w2st + i * 65536, 256, 256);
  }
  transpose(Wp1, 0, wp1t, 256, 256);

  // CSR
  zero_i32_k<<<(N + 255) / 256, 256, 0, stream>>>(cnt, N);
  hist_k<<<(E + 255) / 256, 256, 0, stream>>>(edge, E, cnt, flags);
  int NB = (N + SCAN_CHUNK - 1) / SCAN_CHUNK;
  scan1_k<<<NB, 256, 0, stream>>>(cnt, rowptr, partials, N);
  scan2_k<<<1, 256, 0, stream>>>(partials, NB);
  scan3_k<<<NB, 256, 0, stream>>>(rowptr, partials, N, E);
  zero_i32_k<<<(N + 255) / 256, 256, 0, stream>>>(cnt, N);
  fill_k<<<(E + 255) / 256, 256, 0, stream>>>(edge, E, rowptr, cnt, colidx, flags);
  graph_bounds_k<<<(G + 1 + 255) / 256, 256, 0, stream>>>(batch, N, G, gstart, flags);

  auto gemm = [&](const unsigned short* A, const unsigned short* Bt, const float* bias,
                  unsigned short* Cq, int M, int K, int relu, float* stats) {
    gemm_k<<<dim3((M + 127) / 128, 2), 256, 0, stream>>>(A, Bt, bias, Cq, M, K, relu, stats);
  };

  // ---- layer 0 ----
  prep_k<<<1, 256, 0, stream>>>(b1_0, b2_0, gamma0, beta0, 0, pb1, pb2, pg, pb, gsum, flags);
  gather_fused_k<16, 0><<<(N * 16 + 255) / 256, 256, 0, stream>>>(
      bufY, bnscale, bnshift, rowptr, colidx, bufX, N);
  gemm(bufX, w1_0t, pb1, bufY, N, 128, 1, nullptr);
  gemm(bufY, w2_0t, pb2, bufX, N, 256, 0, gsum);   // v0 + fused BN stats
  bn_finalize_k<<<1, 256, 0, stream>>>(gsum, pg, pb, N, bnscale, bnshift);
  unsigned short* cur = bufX;  // pre-BN v0
  unsigned short* oth = bufY;
  // ---- layers 1..4 ----
  for (int i = 0; i < 4; i++) {
    prep_k<<<1, 256, 0, stream>>>(b1s, b2s, gammas, betas, i * 256, pb1, pb2, pg, pb, gsum, flags);
    gather_fused_k<32, 1><<<(N * 32 + 255) / 256, 256, 0, stream>>>(
        cur, bnscale, bnshift, rowptr, colidx, oth, N);
    gemm(oth, w1st + i * 65536, pb1, cur, N, 256, 1, nullptr);
    gemm(cur, w2st + i * 65536, pb2, oth, N, 256, 0, gsum);  // v_i + BN stats
    bn_finalize_k<<<1, 256, 0, stream>>>(gsum, pg, pb, N, bnscale, bnshift);
    unsigned short* t = cur; cur = oth; oth = t;  // v_i now in cur
  }

  // ---- pool + predictor ----
  copy256_k<<<1, 256, 0, stream>>>(bp1, 0, pb1, flags);
  pool_fused_k<<<G, 256, 0, stream>>>(cur, bnscale, bnshift, gstart, gpool);
  gemm(gpool, wp1t, pb1, p1, G, 256, 1, nullptr);
  pred2_k<<<(G * 12 + 255) / 256, 256, 0, stream>>>(p1, Wp2, bp2, d_out, G, flags);
}

// Round 9
// 1127.678 us; speedup vs baseline: 1.2830x; 1.2339x over previous
//
#include <hip/hip_runtime.h>

// GINModel on MI355X (gfx950). Round 9: fused per-layer MLP kernel.
// t = relu(u@W1+b1) lives only in LDS (64-row stripe, XOR-swizzled chunks);
// v = t@W2+b2 computed immediately (W2 fragments stream from L2).
// Removes 102 MB/layer of t traffic + halves GEMM dispatches.
// K-loops: r8-style global->VGPR register streaming, 2-deep prefetch.
// Epilogue: scattered v stores (r5-proven) + register BN stats (r8-proven).
// fp16 internal storage, fp32 accumulation, dual-width input hardening.

typedef __attribute__((ext_vector_type(4))) float f32x4;
typedef __attribute__((ext_vector_type(8))) _Float16 f16x8;

__device__ __forceinline__ float h2f(unsigned short u) {
  _Float16 h; __builtin_memcpy(&h, &u, 2); return (float)h;
}
__device__ __forceinline__ unsigned short f2h16(float f) {
  _Float16 h = (_Float16)f; unsigned short u; __builtin_memcpy(&u, &h, 2); return u;
}
__device__ __forceinline__ unsigned short f2b(float f) {  // fp32 -> bf16 RNE
  union { float f; unsigned int i; } c; c.f = f;
  unsigned int x = c.i;
  return (unsigned short)((x + 0x7fffu + ((x >> 16) & 1u)) >> 16);
}
__device__ __forceinline__ f16x8 asf16x8(uint4 v) {
  union { uint4 u; f16x8 h; } c; c.u = v; return c.h;
}
__device__ __forceinline__ float lin(const void* p, long long i, int wf32) {
  if (wf32) return ((const float*)p)[i];
  union { unsigned int i; float f; } c;
  c.i = ((unsigned int)((const unsigned short*)p)[i]) << 16;
  return c.f;
}
__device__ __forceinline__ int ldidx(const int* p, long long i, int w64) {
  return w64 ? p[2 * i] : p[i];
}

// flags[0]=w64 (int64 indices), flags[1]=wf32 (fp32 floats)
__global__ void detect_k(const int* __restrict__ edge, const unsigned short* __restrict__ xa,
                         int* __restrict__ flags) {
  if (threadIdx.x != 0 || blockIdx.x != 0) return;
  int nzOdd = 0;
  for (int t = 0; t < 256; t++) if (edge[2 * t + 1] != 0) nzOdd++;
  flags[0] = (nzOdd == 0) ? 1 : 0;
  int plaus = 0;
  for (int t = 0; t < 64; t++) {
    unsigned short w = xa[2 * t];
    int e = (w >> 7) & 0xFF;
    if (w == 0 || (e >= 0x70 && e <= 0x85)) plaus++;
  }
  flags[1] = (plaus < 32) ? 1 : 0;
}

__global__ void zero_i32_k(int* __restrict__ p, int n) {
  int i = blockIdx.x * blockDim.x + threadIdx.x;
  if (i < n) p[i] = 0;
}

// per-layer prep: slice 4x256 params to fp32 + zero BN accumulators
__global__ void prep_k(const void* __restrict__ b1, const void* __restrict__ b2,
                       const void* __restrict__ gm, const void* __restrict__ bt, int eoff,
                       float* __restrict__ pb1, float* __restrict__ pb2,
                       float* __restrict__ pg, float* __restrict__ pb,
                       float* __restrict__ gsum, const int* __restrict__ flags) {
  int wf32 = flags[1], t = threadIdx.x;
  pb1[t] = lin(b1, (long long)eoff + t, wf32);
  pb2[t] = lin(b2, (long long)eoff + t, wf32);
  pg[t]  = lin(gm, (long long)eoff + t, wf32);
  pb[t]  = lin(bt, (long long)eoff + t, wf32);
  gsum[t] = 0.f; gsum[256 + t] = 0.f;
}
__global__ void copy256_k(const void* __restrict__ src, int eoff, float* __restrict__ dst,
                          const int* __restrict__ flags) {
  dst[threadIdx.x] = lin(src, (long long)eoff + threadIdx.x, flags[1]);
}

// input (R x C at element offset, dual width) -> fp16 transposed (C x R)
__global__ void transpose_off_k(const void* __restrict__ src, long long eoff,
                                unsigned short* __restrict__ dst, int R, int C,
                                const int* __restrict__ flags) {
  int wf32 = flags[1];
  __shared__ unsigned short t[32][33];
  int bx = blockIdx.x * 32, by = blockIdx.y * 32;
  int x = bx + threadIdx.x;
  for (int i = 0; i < 32; i += 8) {
    int y = by + threadIdx.y + i;
    if (y < R && x < C)
      t[threadIdx.y + i][threadIdx.x] = f2h16(lin(src, eoff + (long long)y * C + x, wf32));
  }
  __syncthreads();
  int x2 = by + threadIdx.x;
  for (int i = 0; i < 32; i += 8) {
    int y = bx + threadIdx.y + i;
    if (y < C && x2 < R) dst[(long long)y * R + x2] = t[threadIdx.x][threadIdx.y + i];
  }
}

// ---------------- CSR ----------------
__global__ void hist_k(const int* __restrict__ edge, int E, int* __restrict__ cnt,
                       const int* __restrict__ flags) {
  int w64 = flags[0];
  int e = blockIdx.x * blockDim.x + threadIdx.x;
  if (e < E) atomicAdd(&cnt[ldidx(edge, (long long)E + e, w64)], 1);
}
#define SCAN_CHUNK 1024
__global__ void scan1_k(const int* __restrict__ in, int* __restrict__ out,
                        int* __restrict__ partials, int n) {
  __shared__ int sh[256];
  int tid = threadIdx.x;
  int base = blockIdx.x * SCAN_CHUNK + tid * 4;
  int v[4]; int tsum = 0;
#pragma unroll
  for (int i = 0; i < 4; i++) { v[i] = (base + i < n) ? in[base + i] : 0; tsum += v[i]; }
  sh[tid] = tsum; __syncthreads();
  for (int off = 1; off < 256; off <<= 1) {
    int t = (tid >= off) ? sh[tid - off] : 0;
    __syncthreads();
    sh[tid] += t;
    __syncthreads();
  }
  int run = sh[tid] - tsum;
#pragma unroll
  for (int i = 0; i < 4; i++) { if (base + i < n) out[base + i] = run; run += v[i]; }
  if (tid == 255) partials[blockIdx.x] = sh[255];
}
__global__ void scan2_k(int* partials, int B) {
  __shared__ int sh[256];
  int tid = threadIdx.x;
  int orig = (tid < B) ? partials[tid] : 0;
  sh[tid] = orig; __syncthreads();
  for (int off = 1; off < 256; off <<= 1) {
    int t = (tid >= off) ? sh[tid - off] : 0;
    __syncthreads();
    sh[tid] += t;
    __syncthreads();
  }
  if (tid < B) partials[tid] = sh[tid] - orig;
}
__global__ void scan3_k(int* __restrict__ out, const int* __restrict__ partials,
                        int n, int total) {
  int base = blockIdx.x * SCAN_CHUNK + threadIdx.x * 4;
  int add = partials[blockIdx.x];
#pragma unroll
  for (int i = 0; i < 4; i++) { if (base + i < n) out[base + i] += add; }
  if (blockIdx.x == 0 && threadIdx.x == 0) out[n] = total;
}
__global__ void fill_k(const int* __restrict__ edge, int E, const int* __restrict__ rowptr,
                       int* __restrict__ cnt, int* __restrict__ colidx,
                       const int* __restrict__ flags) {
  int w64 = flags[0];
  int e = blockIdx.x * blockDim.x + threadIdx.x;
  if (e >= E) return;
  int s = ldidx(edge, e, w64);
  int d = ldidx(edge, (long long)E + e, w64);
  int p = atomicAdd(&cnt[d], 1);
  colidx[rowptr[d] + p] = s;
}
__global__ void graph_bounds_k(const int* __restrict__ b, int Nn, int G,
                               int* __restrict__ gstart, const int* __restrict__ flags) {
  int w64 = flags[0];
  int g = blockIdx.x * blockDim.x + threadIdx.x;
  if (g > G) return;
  int lo = 0, hi = Nn;
  while (lo < hi) {
    int mid = (lo + hi) >> 1;
    if (ldidx(b, mid, w64) < g) lo = mid + 1; else hi = mid;
  }
  gstart[g] = lo;
}

// x (dual width) -> fp16
__global__ void convert_k(const void* __restrict__ x, unsigned short* __restrict__ xh,
                          long long n, const int* __restrict__ flags) {
  int wf32 = flags[1];
  long long base = ((long long)blockIdx.x * blockDim.x + threadIdx.x) * 4;
  if (base >= n) return;
#pragma unroll
  for (int k = 0; k < 4; k++) xh[base + k] = f2h16(lin(x, base + k, wf32));
}

// fused aggregation: u[i] = hn(i) + sum_{j in nbrs(i)} hn(j)
// hn = APPLY ? relu(v*scale+shift) : v.  LPN lanes per node, 8 fp16 per lane.
template <int LPN, int APPLY>
__global__ void gather_fused_k(const unsigned short* __restrict__ src,
                               const float* __restrict__ scale, const float* __restrict__ shift,
                               const int* __restrict__ rowptr, const int* __restrict__ colidx,
                               unsigned short* __restrict__ u, int Nn) {
  const int F = LPN * 8;
  int gid = blockIdx.x * blockDim.x + threadIdx.x;
  int node = gid / LPN;
  if (node >= Nn) return;
  int fb = (gid % LPN) * 8;
  float sc[8], sh[8];
  if (APPLY) {
#pragma unroll
    for (int k = 0; k < 8; k++) { sc[k] = scale[fb + k]; sh[k] = shift[fb + k]; }
  }
  float acc[8];
  {
    uint4 raw = *(const uint4*)(src + (long long)node * F + fb);
    unsigned int ws[4] = {raw.x, raw.y, raw.z, raw.w};
#pragma unroll
    for (int k = 0; k < 8; k++) {
      float xv = h2f((unsigned short)((ws[k >> 1] >> ((k & 1) * 16)) & 0xffff));
      acc[k] = APPLY ? fmaxf(xv * sc[k] + sh[k], 0.f) : xv;
    }
  }
  int s = rowptr[node], e = rowptr[node + 1];
  for (int j = s; j < e; j++) {
    long long nb = colidx[j];
    uint4 raw = *(const uint4*)(src + nb * F + fb);
    unsigned int ws[4] = {raw.x, raw.y, raw.z, raw.w};
#pragma unroll
    for (int k = 0; k < 8; k++) {
      float xv = h2f((unsigned short)((ws[k >> 1] >> ((k & 1) * 16)) & 0xffff));
      acc[k] += APPLY ? fmaxf(xv * sc[k] + sh[k], 0.f) : xv;
    }
  }
  uint4 o;
  unsigned int wo[4];
#pragma unroll
  for (int p = 0; p < 4; p++)
    wo[p] = (unsigned int)f2h16(acc[2 * p]) | ((unsigned int)f2h16(acc[2 * p + 1]) << 16);
  o.x = wo[0]; o.y = wo[1]; o.z = wo[2]; o.w = wo[3];
  *(uint4*)(u + (long long)node * F + fb) = o;
}

// ---------------- fused MLP: v = (relu(u@W1+b1))@W2 + b2, + BN stats ----------------
// 64-row stripe per block, 4 waves each own a 64-col slice (wn=wave*64) but all
// 64 rows. t (64x256 fp16) lives in LDS with XOR-swizzled 8-elem chunks:
//   addr(row,col) = row*256 + (((col>>3) ^ (row&31))<<3) + (col&7)
// gemm2 A-fragment read: ds_read_b128 at row*256 + (((kt*4+lq)^(row&31))<<3).
__global__ __launch_bounds__(256, 3) void mlp_fused_k(
    const unsigned short* __restrict__ U, const unsigned short* __restrict__ W1t,
    const unsigned short* __restrict__ W2t, const float* __restrict__ pb1,
    const float* __restrict__ pb2, unsigned short* __restrict__ V,
    int M, int K1, float* __restrict__ gsum) {
  __shared__ __align__(16) unsigned short Ts[64 * 256];  // 32 KB
  int m0 = blockIdx.x * 64;
  int tid = threadIdx.x;
  int wave = tid >> 6, lane = tid & 63;
  int wn = wave * 64;
  int lrow = lane & 15, lq = lane >> 4;
  // ---- gemm1 ----
  f32x4 acc[4][4] = {};
  long long aoff[4], boff[4];
#pragma unroll
  for (int r = 0; r < 4; r++) {
    int row = m0 + 16 * r + lrow;
    row = row < M ? row : M - 1;
    aoff[r] = (long long)row * K1 + lq * 8;
    boff[r] = (long long)(wn + 16 * r + lrow) * K1 + lq * 8;  // r used as c-index
  }
  int kt1 = K1 >> 5;  // 4 (layer0) or 8
  uint4 af0[4], af1[4], bf0[4], bf1[4];
#pragma unroll
  for (int r = 0; r < 4; r++) { af0[r] = *(const uint4*)(U + aoff[r]); bf0[r] = *(const uint4*)(W1t + boff[r]); }
#pragma unroll
  for (int r = 0; r < 4; r++) { af1[r] = *(const uint4*)(U + aoff[r] + 32); bf1[r] = *(const uint4*)(W1t + boff[r] + 32); }
  for (int kt = 0; kt < kt1; kt += 2) {
#pragma unroll
    for (int r = 0; r < 4; r++) {
      f16x8 a_ = asf16x8(af0[r]);
#pragma unroll
      for (int c = 0; c < 4; c++)
        acc[r][c] = __builtin_amdgcn_mfma_f32_16x16x32_f16(a_, asf16x8(bf0[c]), acc[r][c], 0, 0, 0);
    }
    if (kt + 2 < kt1) {
      int kb = (kt + 2) << 5;
#pragma unroll
      for (int r = 0; r < 4; r++) { af0[r] = *(const uint4*)(U + aoff[r] + kb); bf0[r] = *(const uint4*)(W1t + boff[r] + kb); }
    }
#pragma unroll
    for (int r = 0; r < 4; r++) {
      f16x8 a_ = asf16x8(af1[r]);
#pragma unroll
      for (int c = 0; c < 4; c++)
        acc[r][c] = __builtin_amdgcn_mfma_f32_16x16x32_f16(a_, asf16x8(bf1[c]), acc[r][c], 0, 0, 0);
    }
    if (kt + 3 < kt1) {
      int kb = (kt + 3) << 5;
#pragma unroll
      for (int r = 0; r < 4; r++) { af1[r] = *(const uint4*)(U + aoff[r] + kb); bf1[r] = *(const uint4*)(W1t + boff[r] + kb); }
    }
  }
  // t -> LDS (bias + relu), C-layout scatter with XOR chunk swizzle
#pragma unroll
  for (int c = 0; c < 4; c++) {
    int col = wn + 16 * c + lrow;
    float bv = pb1[col];
#pragma unroll
    for (int r = 0; r < 4; r++) {
#pragma unroll
      for (int i = 0; i < 4; i++) {
        int rl = 16 * r + lq * 4 + i;
        float v = fmaxf(acc[r][c][i] + bv, 0.f);
        Ts[rl * 256 + ((((col >> 3) ^ (rl & 31)) << 3) | (col & 7))] = f2h16(v);
      }
    }
  }
  __syncthreads();
  // ---- gemm2 (K=256) ----
  f32x4 acc2[4][4] = {};
  long long b2off[4];
#pragma unroll
  for (int c = 0; c < 4; c++) b2off[c] = (long long)(wn + 16 * c + lrow) * 256 + lq * 8;
  uint4 b20[4], b21[4];
#pragma unroll
  for (int c = 0; c < 4; c++) { b20[c] = *(const uint4*)(W2t + b2off[c]); b21[c] = *(const uint4*)(W2t + b2off[c] + 32); }
  for (int kt = 0; kt < 8; kt += 2) {
    f16x8 a_[4];
#pragma unroll
    for (int r = 0; r < 4; r++) {
      int rl = 16 * r + lrow;
      a_[r] = *(const f16x8*)(Ts + rl * 256 + ((((kt << 2) + lq) ^ (rl & 31)) << 3));
    }
#pragma unroll
    for (int r = 0; r < 4; r++)
#pragma unroll
      for (int c = 0; c < 4; c++)
        acc2[r][c] = __builtin_amdgcn_mfma_f32_16x16x32_f16(a_[r], asf16x8(b20[c]), acc2[r][c], 0, 0, 0);
    if (kt + 2 < 8) {
      int kb = (kt + 2) << 5;
#pragma unroll
      for (int c = 0; c < 4; c++) b20[c] = *(const uint4*)(W2t + b2off[c] + kb);
    }
#pragma unroll
    for (int r = 0; r < 4; r++) {
      int rl = 16 * r + lrow;
      a_[r] = *(const f16x8*)(Ts + rl * 256 + (((((kt + 1) << 2) + lq) ^ (rl & 31)) << 3));
    }
#pragma unroll
    for (int r = 0; r < 4; r++)
#pragma unroll
      for (int c = 0; c < 4; c++)
        acc2[r][c] = __builtin_amdgcn_mfma_f32_16x16x32_f16(a_[r], asf16x8(b21[c]), acc2[r][c], 0, 0, 0);
    if (kt + 3 < 8) {
      int kb = (kt + 3) << 5;
#pragma unroll
      for (int c = 0; c < 4; c++) b21[c] = *(const uint4*)(W2t + b2off[c] + kb);
    }
  }
  // ---- epilogue: store v + register-sourced BN stats ----
  float scol[4], qcol[4];
#pragma unroll
  for (int c = 0; c < 4; c++) {
    int col = wn + 16 * c + lrow;
    float bv = pb2[col];
    float s = 0.f, q = 0.f;
#pragma unroll
    for (int r = 0; r < 4; r++) {
#pragma unroll
      for (int i = 0; i < 4; i++) {
        int row = m0 + 16 * r + lq * 4 + i;
        if (row < M) {
          float v = acc2[r][c][i] + bv;
          V[(long long)row * 256 + col] = f2h16(v);
          s += v; q += v * v;
        }
      }
    }
    scol[c] = s; qcol[c] = q;
  }
#pragma unroll
  for (int c = 0; c < 4; c++) {
    scol[c] += __shfl_xor(scol[c], 16); scol[c] += __shfl_xor(scol[c], 32);
    qcol[c] += __shfl_xor(qcol[c], 16); qcol[c] += __shfl_xor(qcol[c], 32);
  }
  float* lf = (float*)Ts;
  __syncthreads();  // done with t data; reuse LDS as 512-float scratch
  lf[tid] = 0.f; lf[256 + tid] = 0.f;
  __syncthreads();
  if (lq == 0) {
#pragma unroll
    for (int c = 0; c < 4; c++) {
      atomicAdd(&lf[wn + 16 * c + lrow], scol[c]);
      atomicAdd(&lf[256 + wn + 16 * c + lrow], qcol[c]);
    }
  }
  __syncthreads();
  atomicAdd(&gsum[tid], lf[tid]);
  atomicAdd(&gsum[256 + tid], lf[256 + tid]);
}

// standalone GEMM (r8 structure) — used only for the small predictor matmul.
__global__ __launch_bounds__(256, 3) void gemm_k(
    const unsigned short* __restrict__ A, const unsigned short* __restrict__ Bt,
    const float* __restrict__ bias, unsigned short* __restrict__ C,
    int M, int K, int relu) {
  int m0 = blockIdx.x * 128, n0 = blockIdx.y * 128;
  int tid = threadIdx.x;
  int wave = tid >> 6, lane = tid & 63;
  int wm = (wave >> 1) * 64, wn = (wave & 1) * 64;
  int lrow = lane & 15, lq = lane >> 4;
  long long aoff[4], boff[4];
#pragma unroll
  for (int r = 0; r < 4; r++) {
    int row = m0 + wm + 16 * r + lrow;
    row = row < M ? row : M - 1;
    aoff[r] = (long long)row * K + lq * 8;
    boff[r] = (long long)(n0 + wn + 16 * r + lrow) * K + lq * 8;
  }
  f32x4 acc[4][4] = {};
  int ktiles = K >> 5;
  uint4 af0[4], af1[4], bf0[4], bf1[4];
#pragma unroll
  for (int r = 0; r < 4; r++) { af0[r] = *(const uint4*)(A + aoff[r]); bf0[r] = *(const uint4*)(Bt + boff[r]); }
#pragma unroll
  for (int r = 0; r < 4; r++) { af1[r] = *(const uint4*)(A + aoff[r] + 32); bf1[r] = *(const uint4*)(Bt + boff[r] + 32); }
  for (int kt = 0; kt < ktiles; kt += 2) {
#pragma unroll
    for (int r = 0; r < 4; r++) {
      f16x8 a_ = asf16x8(af0[r]);
#pragma unroll
      for (int c = 0; c < 4; c++)
        acc[r][c] = __builtin_amdgcn_mfma_f32_16x16x32_f16(a_, asf16x8(bf0[c]), acc[r][c], 0, 0, 0);
    }
    if (kt + 2 < ktiles) {
      int kb2 = (kt + 2) << 5;
#pragma unroll
      for (int r = 0; r < 4; r++) { af0[r] = *(const uint4*)(A + aoff[r] + kb2); bf0[r] = *(const uint4*)(Bt + boff[r] + kb2); }
    }
#pragma unroll
    for (int r = 0; r < 4; r++) {
      f16x8 a_ = asf16x8(af1[r]);
#pragma unroll
      for (int c = 0; c < 4; c++)
        acc[r][c] = __builtin_amdgcn_mfma_f32_16x16x32_f16(a_, asf16x8(bf1[c]), acc[r][c], 0, 0, 0);
    }
    if (kt + 3 < ktiles) {
      int kb3 = (kt + 3) << 5;
#pragma unroll
      for (int r = 0; r < 4; r++) { af1[r] = *(const uint4*)(A + aoff[r] + kb3); bf1[r] = *(const uint4*)(Bt + boff[r] + kb3); }
    }
  }
#pragma unroll
  for (int c = 0; c < 4; c++) {
    int col = n0 + wn + 16 * c + lrow;
    float bv = bias[col];
#pragma unroll
    for (int r = 0; r < 4; r++) {
      int rbase = m0 + wm + 16 * r + lq * 4;
#pragma unroll
      for (int i = 0; i < 4; i++) {
        int row = rbase + i;
        if (row < M) {
          float v = acc[r][c][i] + bv;
          if (relu) v = fmaxf(v, 0.f);
          C[(long long)row * 256 + col] = f2h16(v);
        }
      }
    }
  }
}

__global__ void bn_finalize_k(const float* __restrict__ gsum,
                              const float* __restrict__ pg, const float* __restrict__ pb,
                              int Nn, float* __restrict__ scale, float* __restrict__ shift) {
  int f = threadIdx.x;
  float inv = 1.f / (float)Nn;
  float mean = gsum[f] * inv;
  float var = fmaxf(gsum[256 + f] * inv - mean * mean, 0.f);
  float sc = pg[f] * rsqrtf(var + 1e-5f);
  scale[f] = sc;
  shift[f] = pb[f] - mean * sc;
}

// fused pool: mean over graph rows of relu(v*sc+sh)
__global__ void pool_fused_k(const unsigned short* __restrict__ v, const float* __restrict__ scale,
                             const float* __restrict__ shift, const int* __restrict__ gstart,
                             unsigned short* __restrict__ gout) {
  int g = blockIdx.x, f = threadIdx.x;
  int s = gstart[g], e = gstart[g + 1];
  float sc = scale[f], sh = shift[f];
  float acc = 0.f;
  for (int r = s; r < e; r++) acc += fmaxf(h2f(v[(long long)r * 256 + f]) * sc + sh, 0.f);
  gout[(long long)g * 256 + f] = f2h16(acc / fmaxf((float)(e - s), 1.f));
}
__global__ void pred2_k(const unsigned short* __restrict__ p1, const void* __restrict__ Wp2,
                        const void* __restrict__ bp2, void* __restrict__ out, int G,
                        const int* __restrict__ flags) {
  int wf32 = flags[1];
  int idx = blockIdx.x * blockDim.x + threadIdx.x;
  if (idx >= G * 12) return;
  int g = idx / 12, t = idx - g * 12;
  float acc = lin(bp2, t, wf32);
  const unsigned short* row = p1 + (long long)g * 256;
  for (int k = 0; k < 256; k++) acc += h2f(row[k]) * lin(Wp2, k * 12 + t, wf32);
  if (wf32) ((float*)out)[idx] = acc;
  else      ((unsigned short*)out)[idx] = f2b(acc);
}

extern "C" void kernel_launch(void* const* d_in, const int* in_sizes, int n_in,
                              void* d_out, int out_size, void* d_ws, size_t ws_size,
                              hipStream_t stream) {
  int wb = -1;
  for (int i = 3; i + 15 < n_in; i++) {
    if (in_sizes[i] == 32768 && in_sizes[i + 1] == 256 && in_sizes[i + 2] == 65536 &&
        in_sizes[i + 3] == 256 && in_sizes[i + 4] == 256 && in_sizes[i + 5] == 256 &&
        in_sizes[i + 6] == 262144) { wb = i; break; }
  }
  if (wb < 0) wb = (n_in >= 20) ? 4 : 3;

  const void* x      = d_in[0];
  const int*  edge   = (const int*)d_in[1];
  const int*  batch  = (const int*)d_in[2];
  const void* W1_0   = d_in[wb + 0];
  const void* b1_0   = d_in[wb + 1];
  const void* W2_0   = d_in[wb + 2];
  const void* b2_0   = d_in[wb + 3];
  const void* gamma0 = d_in[wb + 4];
  const void* beta0  = d_in[wb + 5];
  const void* W1s    = d_in[wb + 6];
  const void* b1s    = d_in[wb + 7];
  const void* W2s    = d_in[wb + 8];
  const void* b2s    = d_in[wb + 9];
  const void* gammas = d_in[wb + 10];
  const void* betas  = d_in[wb + 11];
  const void* Wp1    = d_in[wb + 12];
  const void* bp1    = d_in[wb + 13];
  const void* Wp2    = d_in[wb + 14];
  const void* bp2    = d_in[wb + 15];

  const int N = in_sizes[0] / 128;
  const int E = in_sizes[1] / 2;
  const int G = out_size / 12;
  const int H = 256;

  char* w = (char*)d_ws;
  size_t off = 0;
  auto alloc = [&](size_t bytes) -> char* {
    char* p = w + off;
    off += (bytes + 255) & ~(size_t)255;
    return p;
  };
  unsigned short* bufX  = (unsigned short*)alloc((size_t)N * H * 2);  // u (gather out)
  unsigned short* bufY  = (unsigned short*)alloc((size_t)N * H * 2);  // xh then v
  unsigned short* w1_0t = (unsigned short*)alloc((size_t)128 * 256 * 2);
  unsigned short* w2_0t = (unsigned short*)alloc((size_t)256 * 256 * 2);
  unsigned short* w1st  = (unsigned short*)alloc((size_t)4 * 256 * 256 * 2);
  unsigned short* w2st  = (unsigned short*)alloc((size_t)4 * 256 * 256 * 2);
  unsigned short* wp1t  = (unsigned short*)alloc((size_t)256 * 256 * 2);
  int*   rowptr   = (int*)alloc((size_t)(N + 1) * 4);
  int*   cnt      = (int*)alloc((size_t)N * 4);
  int*   colidx   = (int*)alloc((size_t)E * 4);
  int*   partials = (int*)alloc(1024 * 4);
  float* gsum     = (float*)alloc(512 * 4);
  float* bnscale  = (float*)alloc(256 * 4);
  float* bnshift  = (float*)alloc(256 * 4);
  float* pg       = (float*)alloc(256 * 4);
  float* pb       = (float*)alloc(256 * 4);
  float* pb1      = (float*)alloc(256 * 4);
  float* pb2      = (float*)alloc(256 * 4);
  int*   gstart   = (int*)alloc((size_t)(G + 1) * 4);
  int*   flags    = (int*)alloc(256);
  unsigned short* gpool = (unsigned short*)alloc((size_t)G * H * 2);
  unsigned short* p1    = (unsigned short*)alloc((size_t)G * H * 2);
  (void)ws_size; (void)n_in;

  detect_k<<<1, 64, 0, stream>>>(edge, (const unsigned short*)x, flags);

  // x -> fp16 into bufY (dead once layer-0 mlp overwrites bufY with v0)
  convert_k<<<(int)(((long long)N * 128 / 4 + 255) / 256), 256, 0, stream>>>(
      x, bufY, (long long)N * 128, flags);

  dim3 tb(32, 8);
  auto transpose = [&](const void* src, long long eoff, unsigned short* dst, int R, int C) {
    transpose_off_k<<<dim3((C + 31) / 32, (R + 31) / 32), tb, 0, stream>>>(src, eoff, dst, R, C, flags);
  };
  transpose(W1_0, 0, w1_0t, 128, 256);
  transpose(W2_0, 0, w2_0t, 256, 256);
  for (int i = 0; i < 4; i++) {
    transpose(W1s, (long long)i * 65536, w1st + i * 65536, 256, 256);
    transpose(W2s, (long long)i * 65536, w2st + i * 65536, 256, 256);
  }
  transpose(Wp1, 0, wp1t, 256, 256);

  // CSR
  zero_i32_k<<<(N + 255) / 256, 256, 0, stream>>>(cnt, N);
  hist_k<<<(E + 255) / 256, 256, 0, stream>>>(edge, E, cnt, flags);
  int NB = (N + SCAN_CHUNK - 1) / SCAN_CHUNK;
  scan1_k<<<NB, 256, 0, stream>>>(cnt, rowptr, partials, N);
  scan2_k<<<1, 256, 0, stream>>>(partials, NB);
  scan3_k<<<NB, 256, 0, stream>>>(rowptr, partials, N, E);
  zero_i32_k<<<(N + 255) / 256, 256, 0, stream>>>(cnt, N);
  fill_k<<<(E + 255) / 256, 256, 0, stream>>>(edge, E, rowptr, cnt, colidx, flags);
  graph_bounds_k<<<(G + 1 + 255) / 256, 256, 0, stream>>>(batch, N, G, gstart, flags);

  int mgrid = (N + 63) / 64;
  // ---- layer 0 ----
  prep_k<<<1, 256, 0, stream>>>(b1_0, b2_0, gamma0, beta0, 0, pb1, pb2, pg, pb, gsum, flags);
  gather_fused_k<16, 0><<<(N * 16 + 255) / 256, 256, 0, stream>>>(
      bufY, bnscale, bnshift, rowptr, colidx, bufX, N);
  mlp_fused_k<<<mgrid, 256, 0, stream>>>(bufX, w1_0t, w2_0t, pb1, pb2, bufY, N, 128, gsum);
  bn_finalize_k<<<1, 256, 0, stream>>>(gsum, pg, pb, N, bnscale, bnshift);
  // ---- layers 1..4 ---- (v always in bufY, u always in bufX)
  for (int i = 0; i < 4; i++) {
    prep_k<<<1, 256, 0, stream>>>(b1s, b2s, gammas, betas, i * 256, pb1, pb2, pg, pb, gsum, flags);
    gather_fused_k<32, 1><<<(N * 32 + 255) / 256, 256, 0, stream>>>(
        bufY, bnscale, bnshift, rowptr, colidx, bufX, N);
    mlp_fused_k<<<mgrid, 256, 0, stream>>>(bufX, w1st + i * 65536, w2st + i * 65536,
                                           pb1, pb2, bufY, N, 256, gsum);
    bn_finalize_k<<<1, 256, 0, stream>>>(gsum, pg, pb, N, bnscale, bnshift);
  }

  // ---- pool + predictor ----
  copy256_k<<<1, 256, 0, stream>>>(bp1, 0, pb1, flags);
  pool_fused_k<<<G, 256, 0, stream>>>(bufY, bnscale, bnshift, gstart, gpool);
  gemm_k<<<dim3((G + 127) / 128, 2), 256, 0, stream>>>(gpool, wp1t, pb1, p1, G, 256, 1);
  pred2_k<<<(G * 12 + 255) / 256, 256, 0, stream>>>(p1, Wp2, bp2, d_out, G, flags);
}